// Round 1
// baseline (151.349 us; speedup 1.0000x reference)
//
#include <hip/hip_runtime.h>

#define EPSF 1e-4f

typedef __attribute__((ext_vector_type(8))) short short8;
typedef __attribute__((ext_vector_type(4))) float f32x4;

// ---------------- ws layout (float units) ----------------
#define WS_MUNF  0        // 8192 f32: mu_norm [k][d]
#define WS_MUNBF 8192     // 8192 ushort (4096 f32 slots): mu_norm bf16 [k][d]
#define WS_KPOS  12288    // 32 f32
#define WS_SQRTK 12320    // 32 f32
#define WS_PART  12352    // nb * 8256 f32: per-block partials (A[d][k] 8192, S 32, G 32)
#define PART_STRIDE 8256

// ---------------- LDS layout (bytes), spf_main ----------------
// [0,16896)            mun bf16 [32][264]
// [16896 + w*2560)     wT bf16 [32][40] per wave  (w=0..3)
// [0,36864)            post-loop scratch f32 [256][36] (aliases the above)
// [36864,37888)        sg f32 [4][64]
#define LDS_TOTAL 37888

static __device__ __forceinline__ unsigned short f2bf(float f) {
    unsigned u = __float_as_uint(f);
    u += 0x7fffu + ((u >> 16) & 1u);   // round-to-nearest-even
    return (unsigned short)(u >> 16);
}

__global__ void spf_prep(const float* __restrict__ mu, const float* __restrict__ kappa,
                         float* __restrict__ wsf) {
    __shared__ float red[256];
    __shared__ float invl[32];
    int t = threadIdx.x;
    int k = t >> 3, part = t & 7;
    const float* row = mu + k * 256 + part * 32;
    float s = 0.f;
    for (int j = 0; j < 32; ++j) { float v = row[j]; s += v * v; }
    red[t] = s;
    __syncthreads();
    if (t < 32) {
        float tot = 0.f;
        for (int j = 0; j < 8; ++j) tot += red[t * 8 + j];
        invl[t] = 1.0f / fmaxf(sqrtf(tot), EPSF);
        float kp = fmaxf(kappa[t], EPSF);
        wsf[WS_KPOS + t] = kp;
        wsf[WS_SQRTK + t] = sqrtf(kp);
    }
    __syncthreads();
    float inv = invl[k];
    unsigned short* mbf = (unsigned short*)(wsf + WS_MUNBF);
    for (int j = 0; j < 32; ++j) {
        int idx = k * 256 + part * 32 + j;
        float v = mu[idx] * inv;
        wsf[idx] = v;       // f32 normalized mu
        mbf[idx] = f2bf(v); // bf16 normalized mu
    }
}

__global__ void __launch_bounds__(256, 2)
spf_main(const float* __restrict__ x, const float* __restrict__ wsf,
         float* __restrict__ partials, int ntiles, int tilestride) {
    extern __shared__ char lds[];
    unsigned short* mun = (unsigned short*)lds;
    const int tid = threadIdx.x;
    const int wid = tid >> 6, lane = tid & 63;
    const int l15 = lane & 15, g = lane >> 4;
    unsigned short* wT = (unsigned short*)(lds + 16896 + wid * 2560);

    // stage mu_norm bf16 into LDS [32][264]
    {
        const ushort4* src = (const ushort4*)(wsf + WS_MUNBF);
        for (int i = tid; i < 2048; i += 256) {
            ushort4 v = src[i];
            int e = i << 2;
            *(ushort4*)(mun + (e >> 8) * 264 + (e & 255)) = v;
        }
    }
    const float kp0 = wsf[WS_KPOS + l15];
    const float kp1 = wsf[WS_KPOS + 16 + l15];
    __syncthreads();

    const f32x4 fz = {0.f, 0.f, 0.f, 0.f};
    f32x4 acc[2][16];   // A[k = 16h + 4g + r][d = 16dt + l15]
    #pragma unroll
    for (int h = 0; h < 2; ++h)
        #pragma unroll
        for (int dt = 0; dt < 16; ++dt)
            acc[h][dt] = fz;
    float S0 = 0.f, S1 = 0.f, G0 = 0.f, G1 = 0.f;

    for (int tile = blockIdx.x * 4 + wid; tile < ntiles; tile += tilestride) {
        const float* xt = x + (size_t)tile * (32 * 256);
        // ---- GEMM1: rawdot[sample][k] = x_bf16 . mun_bf16, plus f32 row sumsq ----
        f32x4 cc00 = fz, cc01 = fz, cc10 = fz, cc11 = fz;
        float ss0 = 0.f, ss1 = 0.f;
        #pragma unroll
        for (int ch = 0; ch < 8; ++ch) {
            const int off = ch * 32 + g * 8;
            float4 p0 = *(const float4*)(xt + l15 * 256 + off);
            float4 p1 = *(const float4*)(xt + l15 * 256 + off + 4);
            float4 q0 = *(const float4*)(xt + (16 + l15) * 256 + off);
            float4 q1 = *(const float4*)(xt + (16 + l15) * 256 + off + 4);
            ss0 += p0.x*p0.x + p0.y*p0.y + p0.z*p0.z + p0.w*p0.w
                 + p1.x*p1.x + p1.y*p1.y + p1.z*p1.z + p1.w*p1.w;
            ss1 += q0.x*q0.x + q0.y*q0.y + q0.z*q0.z + q0.w*q0.w
                 + q1.x*q1.x + q1.y*q1.y + q1.z*q1.z + q1.w*q1.w;
            short8 a0, a1;
            a0[0]=(short)f2bf(p0.x); a0[1]=(short)f2bf(p0.y); a0[2]=(short)f2bf(p0.z); a0[3]=(short)f2bf(p0.w);
            a0[4]=(short)f2bf(p1.x); a0[5]=(short)f2bf(p1.y); a0[6]=(short)f2bf(p1.z); a0[7]=(short)f2bf(p1.w);
            a1[0]=(short)f2bf(q0.x); a1[1]=(short)f2bf(q0.y); a1[2]=(short)f2bf(q0.z); a1[3]=(short)f2bf(q0.w);
            a1[4]=(short)f2bf(q1.x); a1[5]=(short)f2bf(q1.y); a1[6]=(short)f2bf(q1.z); a1[7]=(short)f2bf(q1.w);
            short8 b0 = *(const short8*)(mun + l15 * 264 + off);
            short8 b1 = *(const short8*)(mun + (16 + l15) * 264 + off);
            cc00 = __builtin_amdgcn_mfma_f32_16x16x32_bf16(a0, b0, cc00, 0, 0, 0);
            cc01 = __builtin_amdgcn_mfma_f32_16x16x32_bf16(a0, b1, cc01, 0, 0, 0);
            cc10 = __builtin_amdgcn_mfma_f32_16x16x32_bf16(a1, b0, cc10, 0, 0, 0);
            cc11 = __builtin_amdgcn_mfma_f32_16x16x32_bf16(a1, b1, cc11, 0, 0, 0);
        }
        // full row sumsq: lane's partial covers its g-quarter; combine across g
        ss0 += __shfl_xor(ss0, 16); ss0 += __shfl_xor(ss0, 32);
        ss1 += __shfl_xor(ss1, 16); ss1 += __shfl_xor(ss1, 32);
        const float inv0 = 1.0f / fmaxf(sqrtf(ss0), EPSF);  // row l15
        const float inv1 = 1.0f / fmaxf(sqrtf(ss1), EPSF);  // row 16+l15

        // ---- softmax over k (lane holds k=l15 and k=16+l15 for sample 4g+r) ----
        #pragma unroll
        for (int sub = 0; sub < 2; ++sub) {
            const f32x4 ck0 = sub ? cc10 : cc00;
            const f32x4 ck1 = sub ? cc11 : cc01;
            const float invsel = sub ? inv1 : inv0;
            #pragma unroll
            for (int r = 0; r < 4; ++r) {
                const float invr = __shfl(invsel, 4 * g + r);  // norm of this sample
                const float c0 = ck0[r] * invr;
                const float c1 = ck1[r] * invr;
                const float l0 = kp0 * c0, l1 = kp1 * c1;
                float m = fmaxf(l0, l1);
                m = fmaxf(m, __shfl_xor(m, 1));
                m = fmaxf(m, __shfl_xor(m, 2));
                m = fmaxf(m, __shfl_xor(m, 4));
                m = fmaxf(m, __shfl_xor(m, 8));
                const float e0 = __expf(l0 - m), e1 = __expf(l1 - m);
                float z = e0 + e1;
                z += __shfl_xor(z, 1);
                z += __shfl_xor(z, 2);
                z += __shfl_xor(z, 4);
                z += __shfl_xor(z, 8);
                const float rz = 1.0f / z;
                const float g0 = e0 * rz, g1 = e1 * rz;
                const float u0 = g0 * rsqrtf(fmaxf(1.0f - c0 * c0 + EPSF, 1e-12f));
                const float u1 = g1 * rsqrtf(fmaxf(1.0f - c1 * c1 + EPSF, 1e-12f));
                S0 += u0 * c0; S1 += u1 * c1;
                G0 += g0 * (kp0 * (1.0f - c0) - 1.0f);
                G1 += g1 * (kp1 * (1.0f - c1) - 1.0f);
                const int srow = sub * 16 + 4 * g + r;
                wT[l15 * 40 + srow]        = f2bf(u0 * invr);  // w~[sample][k] stored [k][sample]
                wT[(16 + l15) * 40 + srow] = f2bf(u1 * invr);
            }
        }
        // ---- GEMM2: A[k][d] += sum_s w~[s][k] * x_bf16[s][d] ----
        const short8 wa0 = *(const short8*)(wT + l15 * 40 + g * 8);
        const short8 wa1 = *(const short8*)(wT + (16 + l15) * 40 + g * 8);
        #pragma unroll
        for (int dt = 0; dt < 16; ++dt) {
            short8 xb;
            #pragma unroll
            for (int e = 0; e < 8; ++e)
                xb[e] = (short)f2bf(xt[(g * 8 + e) * 256 + dt * 16 + l15]);
            acc[0][dt] = __builtin_amdgcn_mfma_f32_16x16x32_bf16(wa0, xb, acc[0][dt], 0, 0, 0);
            acc[1][dt] = __builtin_amdgcn_mfma_f32_16x16x32_bf16(wa1, xb, acc[1][dt], 0, 0, 0);
        }
    }

    // ---- S/G reduce across g, stash per wave ----
    S0 += __shfl_xor(S0, 16); S0 += __shfl_xor(S0, 32);
    S1 += __shfl_xor(S1, 16); S1 += __shfl_xor(S1, 32);
    G0 += __shfl_xor(G0, 16); G0 += __shfl_xor(G0, 32);
    G1 += __shfl_xor(G1, 16); G1 += __shfl_xor(G1, 32);
    {
        float* sg = (float*)(lds + 36864) + wid * 64;
        if (lane < 16) {
            sg[lane] = S0; sg[16 + lane] = S1;
            sg[32 + lane] = G0; sg[48 + lane] = G1;
        }
    }
    __syncthreads();

    // ---- block-level A reduce via LDS scratch [256 d][36] ----
    float* scratch = (float*)lds;
    for (int w = 0; w < 4; ++w) {
        if (wid == w) {
            #pragma unroll
            for (int h = 0; h < 2; ++h)
                #pragma unroll
                for (int dt = 0; dt < 16; ++dt) {
                    float* p = scratch + (dt * 16 + l15) * 36 + h * 16 + 4 * g;
                    if (w == 0) *(f32x4*)p = acc[h][dt];
                    else {
                        f32x4 tv = *(const f32x4*)p;
                        tv += acc[h][dt];
                        *(f32x4*)p = tv;
                    }
                }
        }
        __syncthreads();
    }

    // ---- write per-block partial: A compact [d*32+k], then S[32], G[32] ----
    float* pb = partials + (size_t)blockIdx.x * PART_STRIDE;
    for (int i = tid; i < 2048; i += 256) {
        int base = i << 2;
        *(f32x4*)(pb + base) = *(const f32x4*)(scratch + (base >> 5) * 36 + (base & 31));
    }
    if (tid < 64) {
        const float* sgb = (const float*)(lds + 36864);
        pb[8192 + tid] = sgb[tid] + sgb[64 + tid] + sgb[128 + tid] + sgb[192 + tid];
    }
}

__global__ void spf_finalize(const float* __restrict__ wsf, float* __restrict__ out,
                             int nb, float invN) {
    const int k = blockIdx.x, t = threadIdx.x;
    const float* P = wsf + WS_PART;
    __shared__ float rs[256], rg[256];
    float sP = 0.f, gP = 0.f;
    for (int b = t; b < nb; b += 256) {
        sP += P[(size_t)b * PART_STRIDE + 8192 + k];
        gP += P[(size_t)b * PART_STRIDE + 8224 + k];
    }
    rs[t] = sP; rg[t] = gP;
    __syncthreads();
    for (int off = 128; off > 0; off >>= 1) {
        if (t < off) { rs[t] += rs[t + off]; rg[t] += rg[t + off]; }
        __syncthreads();
    }
    const float Sk = rs[0], Gk = rg[0];
    float sumA = 0.f;
    for (int b = 0; b < nb; ++b)
        sumA += P[(size_t)b * PART_STRIDE + t * 32 + k];
    const float mund = wsf[k * 256 + t];
    out[k * 256 + t] = wsf[WS_SQRTK + k] * (sumA - Sk * mund) * invN;
    if (t == 0) out[8192 + k] = Gk * 0.70710678118654752f * invN;
}

extern "C" void kernel_launch(void* const* d_in, const int* in_sizes, int n_in,
                              void* d_out, int out_size, void* d_ws, size_t ws_size,
                              hipStream_t stream) {
    const float* x = (const float*)d_in[0];
    const float* mu = (const float*)d_in[1];
    const float* kappa = (const float*)d_in[2];
    float* wsf = (float*)d_ws;
    float* out = (float*)d_out;
    const int N = in_sizes[0] / 256;
    const int ntiles = N / 32;
    int nb = 256;
    while (nb > 1 && (size_t)(WS_PART + (size_t)nb * PART_STRIDE) * sizeof(float) > ws_size) nb >>= 1;

    spf_prep<<<1, 256, 0, stream>>>(mu, kappa, wsf);
    spf_main<<<nb, 256, LDS_TOTAL, stream>>>(x, wsf, wsf + WS_PART, ntiles, nb * 4);
    spf_finalize<<<32, 256, 0, stream>>>(wsf, out, nb, 1.0f / (float)N);
}

// Round 2
// 47.667 us; speedup vs baseline: 3.1751x; 3.1751x over previous
//
#include <hip/hip_runtime.h>

#define EPSF 1e-4f

typedef __attribute__((ext_vector_type(8))) short short8;
typedef __attribute__((ext_vector_type(4))) float f32x4;

// ---------------- ws layout (float units) ----------------
#define WS_MUNF  0        // 8192 f32: mu_norm [k][d]
#define WS_MUNBF 8192     // 8192 ushort (4096 f32 slots): mu_norm bf16 [k][d]
#define WS_KPOS  12288    // 32 f32
#define WS_SQRTK 12320    // 32 f32
#define WS_PART  12352    // nb * 8256 f32: per-block partials (A[k*256+d] 8192, S 32, G 32)
#define PART_STRIDE 8256

// ---------------- LDS layout (bytes), spf_main ----------------
// [0,16896)            mun bf16 [32][264]
// [16896 + w*1536)     wT u16 [32][24] per wave (w=0..7) -> ends 29184
// [0,36864)            post-loop scratch f32 [256 d][36] (aliases the above)
// [36864,38912)        sg f32 [8][64]
#define LDS_TOTAL 38912

static __device__ __forceinline__ unsigned short f2bf(float f) {
    unsigned u = __float_as_uint(f);
    u += 0x7fffu + ((u >> 16) & 1u);   // round-to-nearest-even
    return (unsigned short)(u >> 16);
}

__global__ void spf_prep(const float* __restrict__ mu, const float* __restrict__ kappa,
                         float* __restrict__ wsf) {
    __shared__ float red[256];
    __shared__ float invl[32];
    int t = threadIdx.x;
    int k = t >> 3, part = t & 7;
    const float4* row = (const float4*)(mu + k * 256 + part * 32);
    float4 v[8];
    float s = 0.f;
    #pragma unroll
    for (int j = 0; j < 8; ++j) {
        v[j] = row[j];
        s += v[j].x * v[j].x + v[j].y * v[j].y + v[j].z * v[j].z + v[j].w * v[j].w;
    }
    red[t] = s;
    __syncthreads();
    if (t < 32) {
        float tot = 0.f;
        #pragma unroll
        for (int j = 0; j < 8; ++j) tot += red[t * 8 + j];
        invl[t] = 1.0f / fmaxf(sqrtf(tot), EPSF);
        float kp = fmaxf(kappa[t], EPSF);
        wsf[WS_KPOS + t] = kp;
        wsf[WS_SQRTK + t] = sqrtf(kp);
    }
    __syncthreads();
    float inv = invl[k];
    unsigned short* mbf = (unsigned short*)(wsf + WS_MUNBF);
    #pragma unroll
    for (int j = 0; j < 8; ++j) {
        int idx = k * 256 + part * 32 + j * 4;
        float4 nv = { v[j].x * inv, v[j].y * inv, v[j].z * inv, v[j].w * inv };
        *(float4*)(wsf + WS_MUNF + idx) = nv;
        ushort4 b = { f2bf(nv.x), f2bf(nv.y), f2bf(nv.z), f2bf(nv.w) };
        *(ushort4*)(mbf + idx) = b;
    }
}

// 16-sample tiles, 8 waves per block, 1 tile per wave (grid-stride if nb shrinks)
__global__ void __launch_bounds__(512, 2)
spf_main(const float* __restrict__ x, const float* __restrict__ wsf,
         float* __restrict__ partials, int ntiles, int tilestride) {
    extern __shared__ char lds[];
    unsigned short* mun = (unsigned short*)lds;
    const int tid = threadIdx.x;
    const int wid = tid >> 6, lane = tid & 63;
    const int l15 = lane & 15, g = lane >> 4;
    unsigned short* wT = (unsigned short*)(lds + 16896 + wid * 1536);

    // stage mu_norm bf16 into LDS [32][264]
    {
        const ushort4* src = (const ushort4*)(wsf + WS_MUNBF);
        for (int i = tid; i < 2048; i += 512) {
            ushort4 v = src[i];
            int e = i << 2;
            *(ushort4*)(mun + (e >> 8) * 264 + (e & 255)) = v;
        }
    }
    const float kp0 = wsf[WS_KPOS + l15];
    const float kp1 = wsf[WS_KPOS + 16 + l15];
    __syncthreads();

    const f32x4 fz = {0.f, 0.f, 0.f, 0.f};
    const short8 sz = {0, 0, 0, 0, 0, 0, 0, 0};
    f32x4 acc[2][16];   // A[k = 16h + 4g + r][d = 16dt + l15]
    #pragma unroll
    for (int h = 0; h < 2; ++h)
        #pragma unroll
        for (int dt = 0; dt < 16; ++dt)
            acc[h][dt] = fz;
    float S0 = 0.f, S1 = 0.f, G0 = 0.f, G1 = 0.f;

    for (int tile = blockIdx.x * 8 + wid; tile < ntiles; tile += tilestride) {
        const float* xt = x + (size_t)tile * (16 * 256);
        // ---- GEMM1: c[sample 0..15][k 0..31] = x_bf16 . mun_bf16, + f32 row sumsq ----
        f32x4 cc0 = fz, cc1 = fz;
        float ss = 0.f;
        #pragma unroll
        for (int ch = 0; ch < 8; ++ch) {
            const int off = ch * 32 + g * 8;
            float4 p0 = *(const float4*)(xt + l15 * 256 + off);
            float4 p1 = *(const float4*)(xt + l15 * 256 + off + 4);
            ss += p0.x*p0.x + p0.y*p0.y + p0.z*p0.z + p0.w*p0.w
                + p1.x*p1.x + p1.y*p1.y + p1.z*p1.z + p1.w*p1.w;
            short8 a0;
            a0[0]=(short)f2bf(p0.x); a0[1]=(short)f2bf(p0.y); a0[2]=(short)f2bf(p0.z); a0[3]=(short)f2bf(p0.w);
            a0[4]=(short)f2bf(p1.x); a0[5]=(short)f2bf(p1.y); a0[6]=(short)f2bf(p1.z); a0[7]=(short)f2bf(p1.w);
            short8 b0 = *(const short8*)(mun + l15 * 264 + off);
            short8 b1 = *(const short8*)(mun + (16 + l15) * 264 + off);
            cc0 = __builtin_amdgcn_mfma_f32_16x16x32_bf16(a0, b0, cc0, 0, 0, 0);
            cc1 = __builtin_amdgcn_mfma_f32_16x16x32_bf16(a0, b1, cc1, 0, 0, 0);
        }
        ss += __shfl_xor(ss, 16); ss += __shfl_xor(ss, 32);
        const float inv0 = 1.0f / fmaxf(sqrtf(ss), EPSF);  // norm of row l15

        // ---- softmax over k: lane holds k=l15 and k=16+l15 for sample 4g+r ----
        #pragma unroll
        for (int r = 0; r < 4; ++r) {
            const int s = 4 * g + r;
            const float invr = __shfl(inv0, s);
            const float c0 = cc0[r] * invr;
            const float c1 = cc1[r] * invr;
            const float l0 = kp0 * c0, l1 = kp1 * c1;
            float m = fmaxf(l0, l1);
            m = fmaxf(m, __shfl_xor(m, 1));
            m = fmaxf(m, __shfl_xor(m, 2));
            m = fmaxf(m, __shfl_xor(m, 4));
            m = fmaxf(m, __shfl_xor(m, 8));
            const float e0 = __expf(l0 - m), e1 = __expf(l1 - m);
            float z = e0 + e1;
            z += __shfl_xor(z, 1);
            z += __shfl_xor(z, 2);
            z += __shfl_xor(z, 4);
            z += __shfl_xor(z, 8);
            const float rz = 1.0f / z;
            const float g0 = e0 * rz, g1 = e1 * rz;
            const float u0 = g0 * rsqrtf(fmaxf(1.0f - c0 * c0 + EPSF, 1e-12f));
            const float u1 = g1 * rsqrtf(fmaxf(1.0f - c1 * c1 + EPSF, 1e-12f));
            S0 += u0 * c0; S1 += u1 * c1;
            G0 += g0 * (kp0 * (1.0f - c0) - 1.0f);
            G1 += g1 * (kp1 * (1.0f - c1) - 1.0f);
            wT[l15 * 24 + s]        = f2bf(u0 * invr);  // w~[k][sample]
            wT[(16 + l15) * 24 + s] = f2bf(u1 * invr);
        }
        // ---- GEMM2: A[k][d] += sum_s w~[s][k] * x_bf16[s][d]  (kk 16..31 zero) ----
        short8 wa0 = sz, wa1 = sz;
        if (g < 2) {
            wa0 = *(const short8*)(wT + l15 * 24 + g * 8);
            wa1 = *(const short8*)(wT + (16 + l15) * 24 + g * 8);
        }
        #pragma unroll
        for (int dt = 0; dt < 16; ++dt) {
            short8 xb = sz;
            if (g < 2) {
                #pragma unroll
                for (int e = 0; e < 8; ++e)
                    xb[e] = (short)f2bf(xt[(g * 8 + e) * 256 + dt * 16 + l15]);
            }
            acc[0][dt] = __builtin_amdgcn_mfma_f32_16x16x32_bf16(wa0, xb, acc[0][dt], 0, 0, 0);
            acc[1][dt] = __builtin_amdgcn_mfma_f32_16x16x32_bf16(wa1, xb, acc[1][dt], 0, 0, 0);
        }
    }

    // ---- S/G reduce across g, stash per wave ----
    S0 += __shfl_xor(S0, 16); S0 += __shfl_xor(S0, 32);
    S1 += __shfl_xor(S1, 16); S1 += __shfl_xor(S1, 32);
    G0 += __shfl_xor(G0, 16); G0 += __shfl_xor(G0, 32);
    G1 += __shfl_xor(G1, 16); G1 += __shfl_xor(G1, 32);
    {
        float* sg = (float*)(lds + 36864) + wid * 64;
        if (lane < 16) {
            sg[lane] = S0; sg[16 + lane] = S1;
            sg[32 + lane] = G0; sg[48 + lane] = G1;
        }
    }
    __syncthreads();

    // ---- block-level A reduce via LDS scratch [256 d][36] ----
    float* scratch = (float*)lds;
    for (int w = 0; w < 8; ++w) {
        if (wid == w) {
            #pragma unroll
            for (int h = 0; h < 2; ++h)
                #pragma unroll
                for (int dt = 0; dt < 16; ++dt) {
                    float* p = scratch + (dt * 16 + l15) * 36 + h * 16 + 4 * g;
                    if (w == 0) *(f32x4*)p = acc[h][dt];
                    else {
                        f32x4 tv = *(const f32x4*)p;
                        tv += acc[h][dt];
                        *(f32x4*)p = tv;
                    }
                }
        }
        __syncthreads();
    }

    // ---- write per-block partial: A at [k*256+d] (coalesced for reduce), S[32], G[32] ----
    float* pb = partials + (size_t)blockIdx.x * PART_STRIDE;
    for (int i = tid; i < 2048; i += 512) {
        int base = i << 2;
        int k = base >> 8, d0 = base & 255;
        f32x4 v;
        #pragma unroll
        for (int j = 0; j < 4; ++j) v[j] = scratch[(d0 + j) * 36 + k];
        *(f32x4*)(pb + base) = v;
    }
    if (tid < 64) {
        const float* sgb = (const float*)(lds + 36864);
        float ssum = 0.f;
        #pragma unroll
        for (int w = 0; w < 8; ++w) ssum += sgb[w * 64 + tid];
        pb[8192 + tid] = ssum;
    }
}

// stage 1: group-reduce partials, fully coalesced. grid = NG*8 blocks.
__global__ void spf_reduce1(const float* __restrict__ P, float* __restrict__ P2, int gpb) {
    const int grp = blockIdx.x >> 3, ec = blockIdx.x & 7;
    const float* base = P + (size_t)grp * gpb * PART_STRIDE;
    const int elo = ec * 1032, ehi = elo + 1032;
    for (int e = elo + threadIdx.x; e < ehi; e += 256) {
        float s = 0.f;
        #pragma unroll 4
        for (int j = 0; j < gpb; ++j) s += base[(size_t)j * PART_STRIDE + e];
        P2[(size_t)grp * PART_STRIDE + e] = s;
    }
}

// stage 2: final NG-way sum + output math. grid = 33 blocks.
__global__ void spf_finalize2(const float* __restrict__ P2, const float* __restrict__ wsf,
                              float* __restrict__ out, int NG, float invN) {
    const int t = threadIdx.x;
    if (blockIdx.x < 32) {
        const int k = blockIdx.x;
        const int e = k * 256 + t;   // t = d
        float At = 0.f, Sk = 0.f;
        for (int gI = 0; gI < NG; ++gI) {
            At += P2[(size_t)gI * PART_STRIDE + e];
            Sk += P2[(size_t)gI * PART_STRIDE + 8192 + k];
        }
        const float mund = wsf[WS_MUNF + e];
        out[e] = wsf[WS_SQRTK + k] * (At - Sk * mund) * invN;
    } else if (t < 32) {
        float Gk = 0.f;
        for (int gI = 0; gI < NG; ++gI) Gk += P2[(size_t)gI * PART_STRIDE + 8224 + t];
        out[8192 + t] = Gk * 0.70710678118654752f * invN;
    }
}

extern "C" void kernel_launch(void* const* d_in, const int* in_sizes, int n_in,
                              void* d_out, int out_size, void* d_ws, size_t ws_size,
                              hipStream_t stream) {
    const float* x = (const float*)d_in[0];
    const float* mu = (const float*)d_in[1];
    const float* kappa = (const float*)d_in[2];
    float* wsf = (float*)d_ws;
    float* out = (float*)d_out;
    const int N = in_sizes[0] / 256;
    const int ntiles = N / 16;
    int nb = 256;
    while (nb > 32 &&
           (size_t)(WS_PART + (size_t)(nb + 32) * PART_STRIDE) * sizeof(float) > ws_size)
        nb >>= 1;
    const int NG = nb < 32 ? nb : 32;
    float* part = wsf + WS_PART;
    float* P2 = part + (size_t)nb * PART_STRIDE;

    spf_prep<<<1, 256, 0, stream>>>(mu, kappa, wsf);
    spf_main<<<nb, 512, LDS_TOTAL, stream>>>(x, wsf, part, ntiles, nb * 8);
    spf_reduce1<<<NG * 8, 256, 0, stream>>>(part, P2, nb / NG);
    spf_finalize2<<<33, 256, 0, stream>>>(P2, wsf, out, NG, 1.0f / (float)N);
}

// Round 3
// 40.586 us; speedup vs baseline: 3.7291x; 1.1745x over previous
//
#include <hip/hip_runtime.h>

#define EPSF 1e-4f

typedef __attribute__((ext_vector_type(8))) short short8;
typedef __attribute__((ext_vector_type(4))) float f32x4;

#define PSTR 4160u   // u32 per partial block: 4096 packed A + 64 f32 (S[32], G[32])

// ---------------- LDS layout (bytes), spf_main ----------------
// [0,16896)        mun bf16 [32][264]
// [16896,37376)    ccbuf f32x4 [4 w][5 slot][64 lane]   (prep red/invl alias this)
// [37376,47616)    wT u16 [4 w][32 k][40]
#define LDS_TOTAL 47616

static __device__ __forceinline__ unsigned short f2bf(float f) {
    unsigned u = __float_as_uint(f);
    u += 0x7fffu + ((u >> 16) & 1u);   // round-to-nearest-even
    return (unsigned short)(u >> 16);
}
static __device__ __forceinline__ float bflo(unsigned v) { return __uint_as_float(v << 16); }
static __device__ __forceinline__ float bfhi(unsigned v) { return __uint_as_float(v & 0xffff0000u); }

// 32-sample tiles; block = 4 waves, wave w owns d-range [w*64, w*64+64).
__global__ void __launch_bounds__(256, 2)
spf_main(const float* __restrict__ x, const float* __restrict__ mu,
         const float* __restrict__ kappa, unsigned* __restrict__ P, int ntiles) {
    __shared__ char lds[LDS_TOTAL];
    unsigned short* mun = (unsigned short*)lds;
    f32x4* cbase = (f32x4*)(lds + 16896);
    const int tid = threadIdx.x;
    const int wid = tid >> 6, lane = tid & 63;
    const int l15 = lane & 15, g = lane >> 4;
    unsigned short* wTw = (unsigned short*)(lds + 37376 + wid * 2560);
    const int dbase = wid * 64;

    // ---- per-block mu normalization (reads are L2/L3-hot across blocks) ----
    {
        float* red = (float*)(lds + 16896);
        float* invl = red + 256;
        const int kk = tid >> 3, part = tid & 7;
        const float4* row = (const float4*)(mu + kk * 256 + part * 32);
        float4 v[8];
        float s = 0.f;
        #pragma unroll
        for (int j = 0; j < 8; ++j) {
            v[j] = row[j];
            s += v[j].x * v[j].x + v[j].y * v[j].y + v[j].z * v[j].z + v[j].w * v[j].w;
        }
        red[tid] = s;
        __syncthreads();
        if (tid < 32) {
            float tot = 0.f;
            #pragma unroll
            for (int j = 0; j < 8; ++j) tot += red[tid * 8 + j];
            invl[tid] = 1.0f / fmaxf(sqrtf(tot), EPSF);
        }
        __syncthreads();
        const float inv = invl[kk];
        #pragma unroll
        for (int j = 0; j < 8; ++j) {
            ushort4 b = { f2bf(v[j].x * inv), f2bf(v[j].y * inv),
                          f2bf(v[j].z * inv), f2bf(v[j].w * inv) };
            *(ushort4*)(mun + kk * 264 + part * 32 + j * 4) = b;
        }
    }
    const float kp0 = fmaxf(kappa[l15], EPSF);
    const float kp1 = fmaxf(kappa[16 + l15], EPSF);
    __syncthreads();

    const f32x4 fz = {0.f, 0.f, 0.f, 0.f};
    f32x4 acc[2][4];   // A[k = 16h+4g+r][d = dbase + dt*16 + l15]
    #pragma unroll
    for (int h = 0; h < 2; ++h)
        #pragma unroll
        for (int dt = 0; dt < 4; ++dt)
            acc[h][dt] = fz;
    float S0 = 0.f, S1 = 0.f, G0 = 0.f, G1 = 0.f;

    for (int tile = blockIdx.x; tile < ntiles; tile += gridDim.x) {
        const float* xt = x + (size_t)tile * (32 * 256);

        // ---- GEMM1 partial dots over this wave's 64 d's ----
        f32x4 cc00 = fz, cc01 = fz, cc10 = fz, cc11 = fz;
        float ss0 = 0.f, ss1 = 0.f;
        #pragma unroll
        for (int ch = 0; ch < 2; ++ch) {
            const int off = dbase + ch * 32 + g * 8;
            float4 p0 = *(const float4*)(xt + l15 * 256 + off);
            float4 p1 = *(const float4*)(xt + l15 * 256 + off + 4);
            float4 q0 = *(const float4*)(xt + (16 + l15) * 256 + off);
            float4 q1 = *(const float4*)(xt + (16 + l15) * 256 + off + 4);
            ss0 += p0.x*p0.x + p0.y*p0.y + p0.z*p0.z + p0.w*p0.w
                 + p1.x*p1.x + p1.y*p1.y + p1.z*p1.z + p1.w*p1.w;
            ss1 += q0.x*q0.x + q0.y*q0.y + q0.z*q0.z + q0.w*q0.w
                 + q1.x*q1.x + q1.y*q1.y + q1.z*q1.z + q1.w*q1.w;
            short8 a0, a1;
            a0[0]=(short)f2bf(p0.x); a0[1]=(short)f2bf(p0.y); a0[2]=(short)f2bf(p0.z); a0[3]=(short)f2bf(p0.w);
            a0[4]=(short)f2bf(p1.x); a0[5]=(short)f2bf(p1.y); a0[6]=(short)f2bf(p1.z); a0[7]=(short)f2bf(p1.w);
            a1[0]=(short)f2bf(q0.x); a1[1]=(short)f2bf(q0.y); a1[2]=(short)f2bf(q0.z); a1[3]=(short)f2bf(q0.w);
            a1[4]=(short)f2bf(q1.x); a1[5]=(short)f2bf(q1.y); a1[6]=(short)f2bf(q1.z); a1[7]=(short)f2bf(q1.w);
            short8 b0 = *(const short8*)(mun + l15 * 264 + off);
            short8 b1 = *(const short8*)(mun + (16 + l15) * 264 + off);
            cc00 = __builtin_amdgcn_mfma_f32_16x16x32_bf16(a0, b0, cc00, 0, 0, 0);
            cc01 = __builtin_amdgcn_mfma_f32_16x16x32_bf16(a0, b1, cc01, 0, 0, 0);
            cc10 = __builtin_amdgcn_mfma_f32_16x16x32_bf16(a1, b0, cc10, 0, 0, 0);
            cc11 = __builtin_amdgcn_mfma_f32_16x16x32_bf16(a1, b1, cc11, 0, 0, 0);
        }

        // ---- hoisted GEMM2 x loads (L1-hot, independent of softmax) ----
        float xf[4][8];
        #pragma unroll
        for (int dt = 0; dt < 4; ++dt)
            #pragma unroll
            for (int e = 0; e < 8; ++e)
                xf[dt][e] = xt[(g * 8 + e) * 256 + dbase + dt * 16 + l15];
        short8 xb[4];
        #pragma unroll
        for (int dt = 0; dt < 4; ++dt)
            #pragma unroll
            for (int e = 0; e < 8; ++e)
                xb[dt][e] = (short)f2bf(xf[dt][e]);

        // ---- exchange partial cc/ss across the 4 waves ----
        {
            f32x4* cw = cbase + (wid * 5) * 64 + lane;
            cw[0] = cc00; cw[64] = cc01; cw[128] = cc10; cw[192] = cc11;
            *(float2*)(cw + 256) = make_float2(ss0, ss1);
        }
        __syncthreads();
        f32x4 C00 = fz, C01 = fz, C10 = fz, C11 = fz;
        float SS0 = 0.f, SS1 = 0.f;
        #pragma unroll
        for (int w2 = 0; w2 < 4; ++w2) {
            const f32x4* cr = cbase + (w2 * 5) * 64 + lane;
            C00 += cr[0]; C01 += cr[64]; C10 += cr[128]; C11 += cr[192];
            float2 sv = *(const float2*)(cr + 256);
            SS0 += sv.x; SS1 += sv.y;
        }
        __syncthreads();   // ccbuf free for next tile
        SS0 += __shfl_xor(SS0, 16); SS0 += __shfl_xor(SS0, 32);
        SS1 += __shfl_xor(SS1, 16); SS1 += __shfl_xor(SS1, 32);
        const float inv0 = 1.0f / fmaxf(sqrtf(SS0), EPSF);   // row l15
        const float inv1 = 1.0f / fmaxf(sqrtf(SS1), EPSF);   // row 16+l15

        // ---- softmax over k (identical in all waves; each writes own wT) ----
        #pragma unroll
        for (int sub = 0; sub < 2; ++sub) {
            const f32x4 ck0 = sub ? C10 : C00;
            const f32x4 ck1 = sub ? C11 : C01;
            const float invsel = sub ? inv1 : inv0;
            #pragma unroll
            for (int r = 0; r < 4; ++r) {
                const float invr = __shfl(invsel, 4 * g + r);
                const float c0 = ck0[r] * invr;
                const float c1 = ck1[r] * invr;
                const float l0 = kp0 * c0, l1 = kp1 * c1;
                float m = fmaxf(l0, l1);
                m = fmaxf(m, __shfl_xor(m, 1));
                m = fmaxf(m, __shfl_xor(m, 2));
                m = fmaxf(m, __shfl_xor(m, 4));
                m = fmaxf(m, __shfl_xor(m, 8));
                const float e0 = __expf(l0 - m), e1 = __expf(l1 - m);
                float z = e0 + e1;
                z += __shfl_xor(z, 1);
                z += __shfl_xor(z, 2);
                z += __shfl_xor(z, 4);
                z += __shfl_xor(z, 8);
                const float rz = 1.0f / z;
                const float g0 = e0 * rz, g1 = e1 * rz;
                const float u0 = g0 * rsqrtf(fmaxf(1.0f - c0 * c0 + EPSF, 1e-12f));
                const float u1 = g1 * rsqrtf(fmaxf(1.0f - c1 * c1 + EPSF, 1e-12f));
                S0 += u0 * c0; S1 += u1 * c1;
                G0 += g0 * (kp0 * (1.0f - c0) - 1.0f);
                G1 += g1 * (kp1 * (1.0f - c1) - 1.0f);
                const int srow = sub * 16 + 4 * g + r;
                wTw[l15 * 40 + srow]        = f2bf(u0 * invr);  // w~[k][sample]
                wTw[(16 + l15) * 40 + srow] = f2bf(u1 * invr);
            }
        }

        // ---- GEMM2: A[k][d-range] += w~^T x ----
        const short8 wa0 = *(const short8*)(wTw + l15 * 40 + g * 8);
        const short8 wa1 = *(const short8*)(wTw + (16 + l15) * 40 + g * 8);
        #pragma unroll
        for (int dt = 0; dt < 4; ++dt) {
            acc[0][dt] = __builtin_amdgcn_mfma_f32_16x16x32_bf16(wa0, xb[dt], acc[0][dt], 0, 0, 0);
            acc[1][dt] = __builtin_amdgcn_mfma_f32_16x16x32_bf16(wa1, xb[dt], acc[1][dt], 0, 0, 0);
        }
    }

    // ---- epilogue: bf16-packed A partial + f32 S/G ----
    S0 += __shfl_xor(S0, 16); S0 += __shfl_xor(S0, 32);
    S1 += __shfl_xor(S1, 16); S1 += __shfl_xor(S1, 32);
    G0 += __shfl_xor(G0, 16); G0 += __shfl_xor(G0, 32);
    G1 += __shfl_xor(G1, 16); G1 += __shfl_xor(G1, 32);
    unsigned* Pb = P + (size_t)blockIdx.x * PSTR;
    #pragma unroll
    for (int dt = 0; dt < 4; ++dt)
        #pragma unroll
        for (int r = 0; r < 4; ++r) {
            unsigned lo = f2bf(acc[0][dt][r]);
            unsigned hi = f2bf(acc[1][dt][r]);
            Pb[(4 * g + r) * 256 + dbase + dt * 16 + l15] = (hi << 16) | lo;
        }
    if (wid == 0 && lane < 16) {
        float* Sf = (float*)(Pb + 4096);
        Sf[lane] = S0; Sf[16 + lane] = S1;
        Sf[32 + lane] = G0; Sf[48 + lane] = G1;
    }
}

// Fused finalize: blocks 0..255: k-pair (b>>4) x d-chunk (b&15); block 256: G.
__global__ void __launch_bounds__(256)
spf_fin(const unsigned* __restrict__ P, const float* __restrict__ mu,
        const float* __restrict__ kappa, float* __restrict__ out, int nb, float invN) {
    __shared__ float r0[256], r1[256];
    const int b = blockIdx.x, t = threadIdx.x;
    if (b < 256) {
        const int kp = b >> 4, dc = b & 15;
        const int dd = t & 15, bq = t >> 4;
        const int d = dc * 16 + dd;
        float A0 = 0.f, A1 = 0.f;
        for (int b2 = bq; b2 < nb; b2 += 16) {
            unsigned v = P[(size_t)b2 * PSTR + kp * 256 + d];
            A0 += bflo(v); A1 += bfhi(v);
        }
        r0[t] = A0; r1[t] = A1;
        __syncthreads();
        #pragma unroll
        for (int off = 128; off >= 16; off >>= 1) {
            if (t < off) { r0[t] += r0[t + off]; r1[t] += r1[t + off]; }
            __syncthreads();
        }
        const float A0f = r0[dd], A1f = r1[dd];
        __syncthreads();
        // Sk
        float s0 = 0.f, s1 = 0.f;
        for (int b2 = t; b2 < nb; b2 += 256) {
            const float* Sf = (const float*)(P + (size_t)b2 * PSTR + 4096);
            s0 += Sf[kp]; s1 += Sf[16 + kp];
        }
        r0[t] = s0; r1[t] = s1;
        __syncthreads();
        #pragma unroll
        for (int off = 128; off >= 1; off >>= 1) {
            if (t < off) { r0[t] += r0[t + off]; r1[t] += r1[t + off]; }
            __syncthreads();
        }
        const float Sk0 = r0[0], Sk1 = r1[0];
        __syncthreads();
        // mu row norms
        const float m0 = mu[kp * 256 + t], m1 = mu[(16 + kp) * 256 + t];
        r0[t] = m0 * m0; r1[t] = m1 * m1;
        __syncthreads();
        #pragma unroll
        for (int off = 128; off >= 1; off >>= 1) {
            if (t < off) { r0[t] += r0[t + off]; r1[t] += r1[t + off]; }
            __syncthreads();
        }
        const float inv0 = 1.0f / fmaxf(sqrtf(r0[0]), EPSF);
        const float inv1 = 1.0f / fmaxf(sqrtf(r1[0]), EPSF);
        if (t < 16) {
            const float sq0 = sqrtf(fmaxf(kappa[kp], EPSF));
            const float sq1 = sqrtf(fmaxf(kappa[16 + kp], EPSF));
            const int dO = dc * 16 + t;
            out[kp * 256 + dO]        = sq0 * (A0f - Sk0 * mu[kp * 256 + dO] * inv0) * invN;
            out[(16 + kp) * 256 + dO] = sq1 * (A1f - Sk1 * mu[(16 + kp) * 256 + dO] * inv1) * invN;
        }
    } else {
        const int k = t & 31, bq = t >> 5;
        float gs = 0.f;
        for (int b2 = bq; b2 < nb; b2 += 8) {
            const float* Gf = (const float*)(P + (size_t)b2 * PSTR + 4096);
            gs += Gf[32 + k];
        }
        r0[t] = gs;
        __syncthreads();
        #pragma unroll
        for (int off = 128; off >= 32; off >>= 1) {
            if (t < off) r0[t] += r0[t + off];
            __syncthreads();
        }
        if (t < 32) out[8192 + t] = r0[t] * 0.70710678118654752f * invN;
    }
}

extern "C" void kernel_launch(void* const* d_in, const int* in_sizes, int n_in,
                              void* d_out, int out_size, void* d_ws, size_t ws_size,
                              hipStream_t stream) {
    const float* x = (const float*)d_in[0];
    const float* mu = (const float*)d_in[1];
    const float* kappa = (const float*)d_in[2];
    unsigned* P = (unsigned*)d_ws;
    float* out = (float*)d_out;
    const int N = in_sizes[0] / 256;
    const int ntiles = N / 32;
    int nb = ntiles < 512 ? ntiles : 512;
    while (nb > 1 && (size_t)nb * PSTR * 4 > ws_size) nb >>= 1;

    spf_main<<<nb, 256, 0, stream>>>(x, mu, kappa, P, ntiles);
    spf_fin<<<257, 256, 0, stream>>>(P, mu, kappa, out, nb, 1.0f / (float)N);
}

// Round 4
// 37.758 us; speedup vs baseline: 4.0084x; 1.0749x over previous
//
#include <hip/hip_runtime.h>

#define EPSF 1e-4f

typedef __attribute__((ext_vector_type(8))) short short8;
typedef __attribute__((ext_vector_type(4))) float f32x4;

#define PSTR 4160u   // u32 per partial block: 4096 packed A + 64 f32 (S[32], G[32])

// ---------------- LDS layout (bytes), spf_main ----------------
// [0,16896)        mun bf16 [32][264]
// [16896,57856)    ccbuf f32x4 [8 w][5 slot][64 lane]  (prologue red/invl alias this)
// [57856,78336)    wT u16 [8 w][32 k][40]
#define LDS_TOTAL 78336

static __device__ __forceinline__ unsigned short f2bf(float f) {
    unsigned u = __float_as_uint(f);
    u += 0x7fffu + ((u >> 16) & 1u);   // round-to-nearest-even
    return (unsigned short)(u >> 16);
}
static __device__ __forceinline__ float bflo(unsigned v) { return __uint_as_float(v << 16); }
static __device__ __forceinline__ float bfhi(unsigned v) { return __uint_as_float(v & 0xffff0000u); }

// 32-sample tiles; block = 8 waves, wave w owns d-range [w*32, w*32+32).
__global__ void __launch_bounds__(512, 2)
spf_main(const float* __restrict__ x, const float* __restrict__ mu,
         const float* __restrict__ kappa, unsigned* __restrict__ P, int ntiles) {
    __shared__ char lds[LDS_TOTAL];
    unsigned short* mun = (unsigned short*)lds;
    f32x4* cbase = (f32x4*)(lds + 16896);
    const int tid = threadIdx.x;
    const int wid = tid >> 6, lane = tid & 63;
    const int l15 = lane & 15, g = lane >> 4;
    unsigned short* wTw = (unsigned short*)(lds + 57856 + wid * 2560);
    const int dbase = wid * 32;

    // ---- prologue: mu normalization (mu reads are L2-hot across blocks) ----
    {
        float* red = (float*)(lds + 16896);
        float* invl = red + 512;
        const int kk = tid >> 4, part = tid & 15;
        const float4* row = (const float4*)(mu + kk * 256 + part * 16);
        float4 v[4];
        float s = 0.f;
        #pragma unroll
        for (int j = 0; j < 4; ++j) {
            v[j] = row[j];
            s += v[j].x * v[j].x + v[j].y * v[j].y + v[j].z * v[j].z + v[j].w * v[j].w;
        }
        red[tid] = s;
        __syncthreads();
        if (tid < 32) {
            float tot = 0.f;
            #pragma unroll
            for (int j = 0; j < 16; ++j) tot += red[tid * 16 + j];
            invl[tid] = 1.0f / fmaxf(sqrtf(tot), EPSF);
        }
        __syncthreads();
        const float inv = invl[kk];
        #pragma unroll
        for (int j = 0; j < 4; ++j) {
            ushort4 b = { f2bf(v[j].x * inv), f2bf(v[j].y * inv),
                          f2bf(v[j].z * inv), f2bf(v[j].w * inv) };
            *(ushort4*)(mun + kk * 264 + part * 16 + j * 4) = b;
        }
    }
    const float kp0 = fmaxf(kappa[l15], EPSF);
    const float kp1 = fmaxf(kappa[16 + l15], EPSF);
    __syncthreads();

    const f32x4 fz = {0.f, 0.f, 0.f, 0.f};
    f32x4 acc00 = fz, acc01 = fz, acc10 = fz, acc11 = fz;  // A[k=(h?16:0)+4g+r][d=dbase+dt*16+l15]
    float S0 = 0.f, S1 = 0.f, G0 = 0.f, G1 = 0.f;

    // contiguous tile assignment
    const int nbk = gridDim.x;
    const int tpb = ntiles / nbk, rem = ntiles % nbk;
    const int t0 = blockIdx.x * tpb + (blockIdx.x < rem ? blockIdx.x : rem);
    const int cnt = tpb + (blockIdx.x < rem ? 1 : 0);

    const int rowA = l15 * 256 + dbase + g * 8;
    const int rowB = rowA + 16 * 256;
    const float* xt = x + (size_t)t0 * 8192;
    float4 p0, p1, q0, q1;
    if (cnt > 0) {
        p0 = *(const float4*)(xt + rowA); p1 = *(const float4*)(xt + rowA + 4);
        q0 = *(const float4*)(xt + rowB); q1 = *(const float4*)(xt + rowB + 4);
    }

    for (int it = 0; it < cnt; ++it) {
        const float* xcur = xt;
        const float4 cp0 = p0, cp1 = p1, cq0 = q0, cq1 = q1;
        xt += 8192;
        if (it + 1 < cnt) {   // prefetch next tile (retires under exchange+softmax+GEMM2)
            p0 = *(const float4*)(xt + rowA); p1 = *(const float4*)(xt + rowA + 4);
            q0 = *(const float4*)(xt + rowB); q1 = *(const float4*)(xt + rowB + 4);
        }

        // ---- GEMM1 partial dots over this wave's 32 d's ----
        float ss0 = cp0.x*cp0.x + cp0.y*cp0.y + cp0.z*cp0.z + cp0.w*cp0.w
                  + cp1.x*cp1.x + cp1.y*cp1.y + cp1.z*cp1.z + cp1.w*cp1.w;
        float ss1 = cq0.x*cq0.x + cq0.y*cq0.y + cq0.z*cq0.z + cq0.w*cq0.w
                  + cq1.x*cq1.x + cq1.y*cq1.y + cq1.z*cq1.z + cq1.w*cq1.w;
        short8 a0, a1;
        a0[0]=(short)f2bf(cp0.x); a0[1]=(short)f2bf(cp0.y); a0[2]=(short)f2bf(cp0.z); a0[3]=(short)f2bf(cp0.w);
        a0[4]=(short)f2bf(cp1.x); a0[5]=(short)f2bf(cp1.y); a0[6]=(short)f2bf(cp1.z); a0[7]=(short)f2bf(cp1.w);
        a1[0]=(short)f2bf(cq0.x); a1[1]=(short)f2bf(cq0.y); a1[2]=(short)f2bf(cq0.z); a1[3]=(short)f2bf(cq0.w);
        a1[4]=(short)f2bf(cq1.x); a1[5]=(short)f2bf(cq1.y); a1[6]=(short)f2bf(cq1.z); a1[7]=(short)f2bf(cq1.w);
        const short8 b0 = *(const short8*)(mun + l15 * 264 + dbase + g * 8);
        const short8 b1 = *(const short8*)(mun + (16 + l15) * 264 + dbase + g * 8);
        f32x4 cc00 = __builtin_amdgcn_mfma_f32_16x16x32_bf16(a0, b0, fz, 0, 0, 0);
        f32x4 cc01 = __builtin_amdgcn_mfma_f32_16x16x32_bf16(a0, b1, fz, 0, 0, 0);
        f32x4 cc10 = __builtin_amdgcn_mfma_f32_16x16x32_bf16(a1, b0, fz, 0, 0, 0);
        f32x4 cc11 = __builtin_amdgcn_mfma_f32_16x16x32_bf16(a1, b1, fz, 0, 0, 0);

        // ---- hoisted GEMM2 x loads (cache-hot, independent of softmax) ----
        float xf0[8], xf1[8];
        #pragma unroll
        for (int e = 0; e < 8; ++e) {
            xf0[e] = xcur[(g * 8 + e) * 256 + dbase + l15];
            xf1[e] = xcur[(g * 8 + e) * 256 + dbase + 16 + l15];
        }

        // ---- exchange partial cc/ss across the 8 waves ----
        {
            f32x4* cw = cbase + (wid * 5) * 64 + lane;
            cw[0] = cc00; cw[64] = cc01; cw[128] = cc10; cw[192] = cc11;
            *(float2*)(cw + 256) = make_float2(ss0, ss1);
        }
        __syncthreads();
        f32x4 C00 = fz, C01 = fz, C10 = fz, C11 = fz;
        float SS0 = 0.f, SS1 = 0.f;
        #pragma unroll
        for (int w2 = 0; w2 < 8; ++w2) {
            const f32x4* cr = cbase + (w2 * 5) * 64 + lane;
            C00 += cr[0]; C01 += cr[64]; C10 += cr[128]; C11 += cr[192];
            float2 sv = *(const float2*)(cr + 256);
            SS0 += sv.x; SS1 += sv.y;
        }
        __syncthreads();   // ccbuf free for next tile
        SS0 += __shfl_xor(SS0, 16); SS0 += __shfl_xor(SS0, 32);
        SS1 += __shfl_xor(SS1, 16); SS1 += __shfl_xor(SS1, 32);
        const float inv0 = 1.0f / fmaxf(sqrtf(SS0), EPSF);   // row l15
        const float inv1 = 1.0f / fmaxf(sqrtf(SS1), EPSF);   // row 16+l15

        short8 xb0, xb1;
        #pragma unroll
        for (int e = 0; e < 8; ++e) {
            xb0[e] = (short)f2bf(xf0[e]);
            xb1[e] = (short)f2bf(xf1[e]);
        }

        // ---- softmax over k (redundant per wave; each writes its own wT) ----
        #pragma unroll
        for (int sub = 0; sub < 2; ++sub) {
            const f32x4 ck0 = sub ? C10 : C00;
            const f32x4 ck1 = sub ? C11 : C01;
            const float invsel = sub ? inv1 : inv0;
            #pragma unroll
            for (int r = 0; r < 4; ++r) {
                const float invr = __shfl(invsel, 4 * g + r);
                const float c0 = ck0[r] * invr;
                const float c1 = ck1[r] * invr;
                const float l0 = kp0 * c0, l1 = kp1 * c1;
                float m = fmaxf(l0, l1);
                m = fmaxf(m, __shfl_xor(m, 1));
                m = fmaxf(m, __shfl_xor(m, 2));
                m = fmaxf(m, __shfl_xor(m, 4));
                m = fmaxf(m, __shfl_xor(m, 8));
                const float e0 = __expf(l0 - m), e1 = __expf(l1 - m);
                float z = e0 + e1;
                z += __shfl_xor(z, 1);
                z += __shfl_xor(z, 2);
                z += __shfl_xor(z, 4);
                z += __shfl_xor(z, 8);
                const float rz = 1.0f / z;
                const float g0 = e0 * rz, g1 = e1 * rz;
                const float u0 = g0 * rsqrtf(fmaxf(1.0f - c0 * c0 + EPSF, 1e-12f));
                const float u1 = g1 * rsqrtf(fmaxf(1.0f - c1 * c1 + EPSF, 1e-12f));
                S0 += u0 * c0; S1 += u1 * c1;
                G0 += g0 * (kp0 * (1.0f - c0) - 1.0f);
                G1 += g1 * (kp1 * (1.0f - c1) - 1.0f);
                const int srow = sub * 16 + 4 * g + r;
                wTw[l15 * 40 + srow]        = f2bf(u0 * invr);  // w~[k][sample]
                wTw[(16 + l15) * 40 + srow] = f2bf(u1 * invr);
            }
        }

        // ---- GEMM2: A[k][d-range] += w~^T x ----
        const short8 wa0 = *(const short8*)(wTw + l15 * 40 + g * 8);
        const short8 wa1 = *(const short8*)(wTw + (16 + l15) * 40 + g * 8);
        acc00 = __builtin_amdgcn_mfma_f32_16x16x32_bf16(wa0, xb0, acc00, 0, 0, 0);
        acc01 = __builtin_amdgcn_mfma_f32_16x16x32_bf16(wa0, xb1, acc01, 0, 0, 0);
        acc10 = __builtin_amdgcn_mfma_f32_16x16x32_bf16(wa1, xb0, acc10, 0, 0, 0);
        acc11 = __builtin_amdgcn_mfma_f32_16x16x32_bf16(wa1, xb1, acc11, 0, 0, 0);
    }

    // ---- epilogue: bf16-packed A partial + f32 S/G ----
    S0 += __shfl_xor(S0, 16); S0 += __shfl_xor(S0, 32);
    S1 += __shfl_xor(S1, 16); S1 += __shfl_xor(S1, 32);
    G0 += __shfl_xor(G0, 16); G0 += __shfl_xor(G0, 32);
    G1 += __shfl_xor(G1, 16); G1 += __shfl_xor(G1, 32);
    unsigned* Pb = P + (size_t)blockIdx.x * PSTR;
    #pragma unroll
    for (int r = 0; r < 4; ++r) {
        unsigned lo0 = f2bf(acc00[r]), hi0 = f2bf(acc10[r]);
        unsigned lo1 = f2bf(acc01[r]), hi1 = f2bf(acc11[r]);
        Pb[(4 * g + r) * 256 + dbase + l15]      = (hi0 << 16) | lo0;
        Pb[(4 * g + r) * 256 + dbase + 16 + l15] = (hi1 << 16) | lo1;
    }
    if (wid == 0 && lane < 16) {
        float* Sf = (float*)(Pb + 4096);
        Sf[lane] = S0; Sf[16 + lane] = S1;
        Sf[32 + lane] = G0; Sf[48 + lane] = G1;
    }
}

// Fused finalize: blocks 0..255: k-pair (b>>4) x d-chunk (b&15); block 256: G.
__global__ void __launch_bounds__(256)
spf_fin(const unsigned* __restrict__ P, const float* __restrict__ mu,
        const float* __restrict__ kappa, float* __restrict__ out, int nb, float invN) {
    __shared__ float r0[256], r1[256];
    const int b = blockIdx.x, t = threadIdx.x;
    if (b < 256) {
        const int kp = b >> 4, dc = b & 15;
        const int dd = t & 15, bq = t >> 4;
        const int d = dc * 16 + dd;
        float A0 = 0.f, A1 = 0.f;
        for (int b2 = bq; b2 < nb; b2 += 16) {
            unsigned v = P[(size_t)b2 * PSTR + kp * 256 + d];
            A0 += bflo(v); A1 += bfhi(v);
        }
        r0[t] = A0; r1[t] = A1;
        __syncthreads();
        #pragma unroll
        for (int off = 128; off >= 16; off >>= 1) {
            if (t < off) { r0[t] += r0[t + off]; r1[t] += r1[t + off]; }
            __syncthreads();
        }
        const float A0f = r0[dd], A1f = r1[dd];
        __syncthreads();
        // Sk
        float s0 = 0.f, s1 = 0.f;
        for (int b2 = t; b2 < nb; b2 += 256) {
            const float* Sf = (const float*)(P + (size_t)b2 * PSTR + 4096);
            s0 += Sf[kp]; s1 += Sf[16 + kp];
        }
        r0[t] = s0; r1[t] = s1;
        __syncthreads();
        #pragma unroll
        for (int off = 128; off >= 1; off >>= 1) {
            if (t < off) { r0[t] += r0[t + off]; r1[t] += r1[t + off]; }
            __syncthreads();
        }
        const float Sk0 = r0[0], Sk1 = r1[0];
        __syncthreads();
        // mu row norms
        const float m0 = mu[kp * 256 + t], m1 = mu[(16 + kp) * 256 + t];
        r0[t] = m0 * m0; r1[t] = m1 * m1;
        __syncthreads();
        #pragma unroll
        for (int off = 128; off >= 1; off >>= 1) {
            if (t < off) { r0[t] += r0[t + off]; r1[t] += r1[t + off]; }
            __syncthreads();
        }
        const float inv0 = 1.0f / fmaxf(sqrtf(r0[0]), EPSF);
        const float inv1 = 1.0f / fmaxf(sqrtf(r1[0]), EPSF);
        if (t < 16) {
            const float sq0 = sqrtf(fmaxf(kappa[kp], EPSF));
            const float sq1 = sqrtf(fmaxf(kappa[16 + kp], EPSF));
            const int dO = dc * 16 + t;
            out[kp * 256 + dO]        = sq0 * (A0f - Sk0 * mu[kp * 256 + dO] * inv0) * invN;
            out[(16 + kp) * 256 + dO] = sq1 * (A1f - Sk1 * mu[(16 + kp) * 256 + dO] * inv1) * invN;
        }
    } else {
        const int k = t & 31, bq = t >> 5;
        float gs = 0.f;
        for (int b2 = bq; b2 < nb; b2 += 8) {
            const float* Gf = (const float*)(P + (size_t)b2 * PSTR + 4096);
            gs += Gf[32 + k];
        }
        r0[t] = gs;
        __syncthreads();
        #pragma unroll
        for (int off = 128; off >= 32; off >>= 1) {
            if (t < off) r0[t] += r0[t + off];
            __syncthreads();
        }
        if (t < 32) out[8192 + t] = r0[t] * 0.70710678118654752f * invN;
    }
}

extern "C" void kernel_launch(void* const* d_in, const int* in_sizes, int n_in,
                              void* d_out, int out_size, void* d_ws, size_t ws_size,
                              hipStream_t stream) {
    const float* x = (const float*)d_in[0];
    const float* mu = (const float*)d_in[1];
    const float* kappa = (const float*)d_in[2];
    unsigned* P = (unsigned*)d_ws;
    float* out = (float*)d_out;
    const int N = in_sizes[0] / 256;
    const int ntiles = N / 32;
    int nb = ntiles < 256 ? ntiles : 256;
    while (nb > 1 && (size_t)nb * PSTR * 4 > ws_size) nb >>= 1;

    spf_main<<<nb, 512, 0, stream>>>(x, mu, kappa, P, ntiles);
    spf_fin<<<257, 256, 0, stream>>>(P, mu, kappa, out, nb, 1.0f / (float)N);
}

// Round 5
// 37.703 us; speedup vs baseline: 4.0142x; 1.0015x over previous
//
#include <hip/hip_runtime.h>

#define EPSF 1e-4f

typedef __attribute__((ext_vector_type(8))) short short8;
typedef __attribute__((ext_vector_type(4))) float f32x4;

#define PSTR 4160u   // u32 per partial block: 4096 packed A + 64 f32 (S[32], G[32])

// ---------------- LDS layout (bytes), spf_main ----------------
// [0,16896)       mun bf16 [32][264]
// [16896,49664)   cpart f32 [8 w][32 s][32 k]   (prologue red/invl alias)
// [49664,50688)   ssg f32 [8 w][32 s]           (g-prereduced row sumsq)
// [50688,53248)   wT u16 [32 k][40 s]           (shared across waves)
// [53248,55296)   sgbuf f32 [8 w][64]           (epilogue S/G)
#define LDS_TOTAL 55296

static __device__ __forceinline__ unsigned short f2bf(float f) {
    unsigned u = __float_as_uint(f);
    u += 0x7fffu + ((u >> 16) & 1u);   // round-to-nearest-even
    return (unsigned short)(u >> 16);
}
static __device__ __forceinline__ float bflo(unsigned v) { return __uint_as_float(v << 16); }
static __device__ __forceinline__ float bfhi(unsigned v) { return __uint_as_float(v & 0xffff0000u); }

// 32-sample tiles; block = 8 waves; GEMM d-split (wave w owns d in [32w,32w+32)),
// softmax s-split (wave w owns samples 4w..4w+3).
__global__ void __launch_bounds__(512, 4)
spf_main(const float* __restrict__ x, const float* __restrict__ mu,
         const float* __restrict__ kappa, unsigned* __restrict__ P, int ntiles) {
    __shared__ char lds[LDS_TOTAL];
    unsigned short* mun = (unsigned short*)lds;
    float* cpartf = (float*)(lds + 16896);
    float* ssg = (float*)(lds + 49664);
    unsigned short* wTs = (unsigned short*)(lds + 50688);
    float* sgbuf = (float*)(lds + 53248);
    const int tid = threadIdx.x;
    const int wid = tid >> 6, lane = tid & 63;
    const int l15 = lane & 15, g = lane >> 4;
    const int dbase = wid * 32;

    // ---- prologue: mu normalization into LDS (mu reads L2-hot across blocks) ----
    {
        float* red = cpartf;          // 512 f32 scratch (aliases cpart)
        float* invl = red + 512;
        const int kk = tid >> 4, part = tid & 15;
        const float4* row = (const float4*)(mu + kk * 256 + part * 16);
        float4 v[4];
        float s = 0.f;
        #pragma unroll
        for (int j = 0; j < 4; ++j) {
            v[j] = row[j];
            s += v[j].x * v[j].x + v[j].y * v[j].y + v[j].z * v[j].z + v[j].w * v[j].w;
        }
        red[tid] = s;
        __syncthreads();
        if (tid < 32) {
            float tot = 0.f;
            #pragma unroll
            for (int j = 0; j < 16; ++j) tot += red[tid * 16 + j];
            invl[tid] = 1.0f / fmaxf(sqrtf(tot), EPSF);
        }
        __syncthreads();
        const float inv = invl[kk];
        #pragma unroll
        for (int j = 0; j < 4; ++j) {
            ushort4 b = { f2bf(v[j].x * inv), f2bf(v[j].y * inv),
                          f2bf(v[j].z * inv), f2bf(v[j].w * inv) };
            *(ushort4*)(mun + kk * 264 + part * 16 + j * 4) = b;
        }
    }
    const float kpv = fmaxf(kappa[lane & 31], EPSF);   // kappa for k = lane&31
    __syncthreads();

    const f32x4 fz = {0.f, 0.f, 0.f, 0.f};
    f32x4 acc00 = fz, acc01 = fz, acc10 = fz, acc11 = fz;
    float Sacc = 0.f, Gacc = 0.f;   // per lane: k = lane&31

    // contiguous tile assignment
    const int nbk = gridDim.x;
    const int tpb = ntiles / nbk, rem = ntiles % nbk;
    const int t0 = blockIdx.x * tpb + (blockIdx.x < rem ? blockIdx.x : rem);
    const int cnt = tpb + (blockIdx.x < rem ? 1 : 0);

    const int rowA = l15 * 256 + dbase + g * 8;
    const int rowB = rowA + 16 * 256;
    const float* xt = x + (size_t)t0 * 8192;
    float4 p0, p1, q0, q1;
    if (cnt > 0) {
        p0 = *(const float4*)(xt + rowA); p1 = *(const float4*)(xt + rowA + 4);
        q0 = *(const float4*)(xt + rowB); q1 = *(const float4*)(xt + rowB + 4);
    }

    for (int it = 0; it < cnt; ++it) {
        const float* xcur = xt;
        const float4 cp0 = p0, cp1 = p1, cq0 = q0, cq1 = q1;
        xt += 8192;
        if (it + 1 < cnt) {   // prefetch next tile
            p0 = *(const float4*)(xt + rowA); p1 = *(const float4*)(xt + rowA + 4);
            q0 = *(const float4*)(xt + rowB); q1 = *(const float4*)(xt + rowB + 4);
        }

        // ---- phase A: GEMM1 partial dots over this wave's 32 d's ----
        float ss0 = cp0.x*cp0.x + cp0.y*cp0.y + cp0.z*cp0.z + cp0.w*cp0.w
                  + cp1.x*cp1.x + cp1.y*cp1.y + cp1.z*cp1.z + cp1.w*cp1.w;
        float ss1 = cq0.x*cq0.x + cq0.y*cq0.y + cq0.z*cq0.z + cq0.w*cq0.w
                  + cq1.x*cq1.x + cq1.y*cq1.y + cq1.z*cq1.z + cq1.w*cq1.w;
        short8 a0, a1;
        a0[0]=(short)f2bf(cp0.x); a0[1]=(short)f2bf(cp0.y); a0[2]=(short)f2bf(cp0.z); a0[3]=(short)f2bf(cp0.w);
        a0[4]=(short)f2bf(cp1.x); a0[5]=(short)f2bf(cp1.y); a0[6]=(short)f2bf(cp1.z); a0[7]=(short)f2bf(cp1.w);
        a1[0]=(short)f2bf(cq0.x); a1[1]=(short)f2bf(cq0.y); a1[2]=(short)f2bf(cq0.z); a1[3]=(short)f2bf(cq0.w);
        a1[4]=(short)f2bf(cq1.x); a1[5]=(short)f2bf(cq1.y); a1[6]=(short)f2bf(cq1.z); a1[7]=(short)f2bf(cq1.w);
        const short8 b0 = *(const short8*)(mun + l15 * 264 + dbase + g * 8);
        const short8 b1 = *(const short8*)(mun + (16 + l15) * 264 + dbase + g * 8);
        f32x4 cc00 = __builtin_amdgcn_mfma_f32_16x16x32_bf16(a0, b0, fz, 0, 0, 0);
        f32x4 cc01 = __builtin_amdgcn_mfma_f32_16x16x32_bf16(a0, b1, fz, 0, 0, 0);
        f32x4 cc10 = __builtin_amdgcn_mfma_f32_16x16x32_bf16(a1, b0, fz, 0, 0, 0);
        f32x4 cc11 = __builtin_amdgcn_mfma_f32_16x16x32_bf16(a1, b1, fz, 0, 0, 0);
        ss0 += __shfl_xor(ss0, 16); ss0 += __shfl_xor(ss0, 32);
        ss1 += __shfl_xor(ss1, 16); ss1 += __shfl_xor(ss1, 32);

        // scatter partial c into own slab: c[s][k], s=sample, k=cluster
        float* cp = cpartf + wid * 1024;
        #pragma unroll
        for (int r = 0; r < 4; ++r) {
            cp[(4 * g + r) * 32 + l15]           = cc00[r];
            cp[(4 * g + r) * 32 + 16 + l15]      = cc01[r];
            cp[(16 + 4 * g + r) * 32 + l15]      = cc10[r];
            cp[(16 + 4 * g + r) * 32 + 16 + l15] = cc11[r];
        }
        if (g == 0) {
            ssg[wid * 32 + l15] = ss0;
            ssg[wid * 32 + 16 + l15] = ss1;
        }
        __syncthreads();

        // ---- phase C: split softmax — wave w owns samples 4w..4w+3 ----
        #pragma unroll
        for (int p = 0; p < 2; ++p) {
            const int s = 4 * wid + 2 * p + (lane >> 5);
            const int kk = lane & 31;
            float craw = 0.f, sss = 0.f;
            #pragma unroll
            for (int w2 = 0; w2 < 8; ++w2) {
                craw += cpartf[w2 * 1024 + s * 32 + kk];
                sss += ssg[w2 * 32 + s];
            }
            const float inv = 1.0f / fmaxf(sqrtf(sss), EPSF);
            const float c = craw * inv;
            const float l = kpv * c;
            float m = l;
            m = fmaxf(m, __shfl_xor(m, 1));
            m = fmaxf(m, __shfl_xor(m, 2));
            m = fmaxf(m, __shfl_xor(m, 4));
            m = fmaxf(m, __shfl_xor(m, 8));
            m = fmaxf(m, __shfl_xor(m, 16));
            const float e = __expf(l - m);
            float z = e;
            z += __shfl_xor(z, 1);
            z += __shfl_xor(z, 2);
            z += __shfl_xor(z, 4);
            z += __shfl_xor(z, 8);
            z += __shfl_xor(z, 16);
            const float gam = e / z;
            const float u = gam * rsqrtf(fmaxf(1.0f - c * c + EPSF, 1e-12f));
            Sacc += u * c;
            Gacc += gam * (kpv * (1.0f - c) - 1.0f);
            wTs[kk * 40 + s] = f2bf(u * inv);
        }
        __syncthreads();

        // ---- phase D: GEMM2: A[k][own 32 d's] += w~^T x ----
        const short8 wa0 = *(const short8*)(wTs + l15 * 40 + g * 8);
        const short8 wa1 = *(const short8*)(wTs + (16 + l15) * 40 + g * 8);
        float xf0[8], xf1[8];
        #pragma unroll
        for (int e = 0; e < 8; ++e) {
            xf0[e] = xcur[(g * 8 + e) * 256 + dbase + l15];
            xf1[e] = xcur[(g * 8 + e) * 256 + dbase + 16 + l15];
        }
        short8 xb0, xb1;
        #pragma unroll
        for (int e = 0; e < 8; ++e) {
            xb0[e] = (short)f2bf(xf0[e]);
            xb1[e] = (short)f2bf(xf1[e]);
        }
        acc00 = __builtin_amdgcn_mfma_f32_16x16x32_bf16(wa0, xb0, acc00, 0, 0, 0);
        acc01 = __builtin_amdgcn_mfma_f32_16x16x32_bf16(wa0, xb1, acc01, 0, 0, 0);
        acc10 = __builtin_amdgcn_mfma_f32_16x16x32_bf16(wa1, xb0, acc10, 0, 0, 0);
        acc11 = __builtin_amdgcn_mfma_f32_16x16x32_bf16(wa1, xb1, acc11, 0, 0, 0);
    }

    // ---- epilogue: S/G block-reduce + bf16-packed A partial ----
    Sacc += __shfl_xor(Sacc, 32);
    Gacc += __shfl_xor(Gacc, 32);
    if (lane < 32) {
        sgbuf[wid * 64 + lane] = Sacc;
        sgbuf[wid * 64 + 32 + lane] = Gacc;
    }
    __syncthreads();
    unsigned* Pb = P + (size_t)blockIdx.x * PSTR;
    #pragma unroll
    for (int r = 0; r < 4; ++r) {
        unsigned lo0 = f2bf(acc00[r]), hi0 = f2bf(acc10[r]);
        unsigned lo1 = f2bf(acc01[r]), hi1 = f2bf(acc11[r]);
        Pb[(4 * g + r) * 256 + dbase + l15]      = (hi0 << 16) | lo0;
        Pb[(4 * g + r) * 256 + dbase + 16 + l15] = (hi1 << 16) | lo1;
    }
    if (tid < 64) {
        float v = 0.f;
        #pragma unroll
        for (int w = 0; w < 8; ++w) v += sgbuf[w * 64 + tid];
        ((float*)(Pb + 4096))[tid] = v;   // [0..31]=S_k, [32..63]=G_k
    }
}

// Fused finalize: blocks 0..255: k-pair (b>>4) x d-chunk (b&15); block 256: G.
__global__ void __launch_bounds__(256)
spf_fin(const unsigned* __restrict__ P, const float* __restrict__ mu,
        const float* __restrict__ kappa, float* __restrict__ out, int nb, float invN) {
    __shared__ float r0[256], r1[256];
    const int b = blockIdx.x, t = threadIdx.x;
    if (b < 256) {
        const int kp = b >> 4, dc = b & 15;
        const int dd = t & 15, bq = t >> 4;
        const int d = dc * 16 + dd;
        float A0 = 0.f, A1 = 0.f;
        for (int b2 = bq; b2 < nb; b2 += 16) {
            unsigned v = P[(size_t)b2 * PSTR + kp * 256 + d];
            A0 += bflo(v); A1 += bfhi(v);
        }
        r0[t] = A0; r1[t] = A1;
        __syncthreads();
        #pragma unroll
        for (int off = 128; off >= 16; off >>= 1) {
            if (t < off) { r0[t] += r0[t + off]; r1[t] += r1[t + off]; }
            __syncthreads();
        }
        const float A0f = r0[dd], A1f = r1[dd];
        __syncthreads();
        // Sk
        float s0 = 0.f, s1 = 0.f;
        for (int b2 = t; b2 < nb; b2 += 256) {
            const float* Sf = (const float*)(P + (size_t)b2 * PSTR + 4096);
            s0 += Sf[kp]; s1 += Sf[16 + kp];
        }
        r0[t] = s0; r1[t] = s1;
        __syncthreads();
        #pragma unroll
        for (int off = 128; off >= 1; off >>= 1) {
            if (t < off) { r0[t] += r0[t + off]; r1[t] += r1[t + off]; }
            __syncthreads();
        }
        const float Sk0 = r0[0], Sk1 = r1[0];
        __syncthreads();
        // mu row norms
        const float m0 = mu[kp * 256 + t], m1 = mu[(16 + kp) * 256 + t];
        r0[t] = m0 * m0; r1[t] = m1 * m1;
        __syncthreads();
        #pragma unroll
        for (int off = 128; off >= 1; off >>= 1) {
            if (t < off) { r0[t] += r0[t + off]; r1[t] += r1[t + off]; }
            __syncthreads();
        }
        const float inv0 = 1.0f / fmaxf(sqrtf(r0[0]), EPSF);
        const float inv1 = 1.0f / fmaxf(sqrtf(r1[0]), EPSF);
        if (t < 16) {
            const float sq0 = sqrtf(fmaxf(kappa[kp], EPSF));
            const float sq1 = sqrtf(fmaxf(kappa[16 + kp], EPSF));
            const int dO = dc * 16 + t;
            out[kp * 256 + dO]        = sq0 * (A0f - Sk0 * mu[kp * 256 + dO] * inv0) * invN;
            out[(16 + kp) * 256 + dO] = sq1 * (A1f - Sk1 * mu[(16 + kp) * 256 + dO] * inv1) * invN;
        }
    } else {
        const int k = t & 31, bq = t >> 5;
        float gs = 0.f;
        for (int b2 = bq; b2 < nb; b2 += 8) {
            const float* Gf = (const float*)(P + (size_t)b2 * PSTR + 4096);
            gs += Gf[32 + k];
        }
        r0[t] = gs;
        __syncthreads();
        #pragma unroll
        for (int off = 128; off >= 32; off >>= 1) {
            if (t < off) r0[t] += r0[t + off];
            __syncthreads();
        }
        if (t < 32) out[8192 + t] = r0[t] * 0.70710678118654752f * invN;
    }
}

extern "C" void kernel_launch(void* const* d_in, const int* in_sizes, int n_in,
                              void* d_out, int out_size, void* d_ws, size_t ws_size,
                              hipStream_t stream) {
    const float* x = (const float*)d_in[0];
    const float* mu = (const float*)d_in[1];
    const float* kappa = (const float*)d_in[2];
    unsigned* P = (unsigned*)d_ws;
    float* out = (float*)d_out;
    const int N = in_sizes[0] / 256;
    const int ntiles = N / 32;
    int nb = ntiles < 512 ? ntiles : 512;
    while (nb > 1 && (size_t)nb * PSTR * 4 > ws_size) nb >>= 1;

    spf_main<<<nb, 512, 0, stream>>>(x, mu, kappa, P, ntiles);
    spf_fin<<<257, 256, 0, stream>>>(P, mu, kappa, out, nb, 1.0f / (float)N);
}

// Round 7
// 37.696 us; speedup vs baseline: 4.0150x; 1.0002x over previous
//
#include <hip/hip_runtime.h>

#define EPSF 1e-4f

typedef __attribute__((ext_vector_type(8))) short short8;
typedef __attribute__((ext_vector_type(4))) float f32x4;

#define PSTR 4160u   // u32 per partial block: 4096 packed A + 64 f32 (S[32], G[32])

// ---------------- LDS layout (bytes), spf_main ----------------
// [0,16896)       mun bf16 [32][264]
// [16896,49664)   cpart f32 [8 w][32 s][32 k]   (prologue red/invl alias)
// [49664,50688)   ssg f32 [8 w][32 s]           (g-prereduced row sumsq)
// [50688,53248)   wT u16 [32 k][40 s]           (shared across waves)
// [53248,55296)   sgbuf f32 [8 w][64]           (epilogue S/G)
#define LDS_TOTAL 55296

static __device__ __forceinline__ unsigned short f2bf(float f) {
    unsigned u = __float_as_uint(f);
    u += 0x7fffu + ((u >> 16) & 1u);   // round-to-nearest-even
    return (unsigned short)(u >> 16);
}
static __device__ __forceinline__ float bflo(unsigned v) { return __uint_as_float(v << 16); }
static __device__ __forceinline__ float bfhi(unsigned v) { return __uint_as_float(v & 0xffff0000u); }

// 32-sample tiles; block = 8 waves; GEMM d-split (wave w owns d in [32w,32w+32)),
// softmax s-split (wave w owns samples 4w..4w+3).
__global__ void __launch_bounds__(512, 4)
spf_main(const float* __restrict__ x, const float* __restrict__ mu,
         const float* __restrict__ kappa, unsigned* __restrict__ P, int ntiles) {
    __shared__ char lds[LDS_TOTAL];
    unsigned short* mun = (unsigned short*)lds;
    float* cpartf = (float*)(lds + 16896);
    float* ssg = (float*)(lds + 49664);
    unsigned short* wTs = (unsigned short*)(lds + 50688);
    float* sgbuf = (float*)(lds + 53248);
    const int tid = threadIdx.x;
    const int wid = tid >> 6, lane = tid & 63;
    const int l15 = lane & 15, g = lane >> 4;
    const int dbase = wid * 32;

    // ---- prologue: mu normalization into LDS (mu reads L2-hot across blocks) ----
    {
        float* red = cpartf;          // 512 f32 scratch (aliases cpart)
        float* invl = red + 512;
        const int kk = tid >> 4, part = tid & 15;
        const float4* row = (const float4*)(mu + kk * 256 + part * 16);
        float4 v[4];
        float s = 0.f;
        #pragma unroll
        for (int j = 0; j < 4; ++j) {
            v[j] = row[j];
            s += v[j].x * v[j].x + v[j].y * v[j].y + v[j].z * v[j].z + v[j].w * v[j].w;
        }
        red[tid] = s;
        __syncthreads();
        if (tid < 32) {
            float tot = 0.f;
            #pragma unroll
            for (int j = 0; j < 16; ++j) tot += red[tid * 16 + j];
            invl[tid] = 1.0f / fmaxf(sqrtf(tot), EPSF);
        }
        __syncthreads();
        const float inv = invl[kk];
        #pragma unroll
        for (int j = 0; j < 4; ++j) {
            ushort4 b = { f2bf(v[j].x * inv), f2bf(v[j].y * inv),
                          f2bf(v[j].z * inv), f2bf(v[j].w * inv) };
            *(ushort4*)(mun + kk * 264 + part * 16 + j * 4) = b;
        }
    }
    const float kpv = fmaxf(kappa[lane & 31], EPSF);   // kappa for k = lane&31
    __syncthreads();

    const f32x4 fz = {0.f, 0.f, 0.f, 0.f};
    f32x4 acc00 = fz, acc01 = fz, acc10 = fz, acc11 = fz;
    float Sacc = 0.f, Gacc = 0.f;   // per lane: k = lane&31

    // contiguous tile assignment
    const int nbk = gridDim.x;
    const int tpb = ntiles / nbk, rem = ntiles % nbk;
    const int t0 = blockIdx.x * tpb + (blockIdx.x < rem ? blockIdx.x : rem);
    const int cnt = tpb + (blockIdx.x < rem ? 1 : 0);

    const int rowA = l15 * 256 + dbase + g * 8;
    const int rowB = rowA + 16 * 256;
    const float* xt = x + (size_t)t0 * 8192;
    float4 p0, p1, q0, q1;
    if (cnt > 0) {
        p0 = *(const float4*)(xt + rowA); p1 = *(const float4*)(xt + rowA + 4);
        q0 = *(const float4*)(xt + rowB); q1 = *(const float4*)(xt + rowB + 4);
    }

    for (int it = 0; it < cnt; ++it) {
        const float* xcur = xt;
        const float4 cp0 = p0, cp1 = p1, cq0 = q0, cq1 = q1;
        xt += 8192;
        if (it + 1 < cnt) {   // prefetch next tile
            p0 = *(const float4*)(xt + rowA); p1 = *(const float4*)(xt + rowA + 4);
            q0 = *(const float4*)(xt + rowB); q1 = *(const float4*)(xt + rowB + 4);
        }

        // ---- phase A: GEMM1 partial dots over this wave's 32 d's ----
        float ss0 = cp0.x*cp0.x + cp0.y*cp0.y + cp0.z*cp0.z + cp0.w*cp0.w
                  + cp1.x*cp1.x + cp1.y*cp1.y + cp1.z*cp1.z + cp1.w*cp1.w;
        float ss1 = cq0.x*cq0.x + cq0.y*cq0.y + cq0.z*cq0.z + cq0.w*cq0.w
                  + cq1.x*cq1.x + cq1.y*cq1.y + cq1.z*cq1.z + cq1.w*cq1.w;
        short8 a0, a1;
        a0[0]=(short)f2bf(cp0.x); a0[1]=(short)f2bf(cp0.y); a0[2]=(short)f2bf(cp0.z); a0[3]=(short)f2bf(cp0.w);
        a0[4]=(short)f2bf(cp1.x); a0[5]=(short)f2bf(cp1.y); a0[6]=(short)f2bf(cp1.z); a0[7]=(short)f2bf(cp1.w);
        a1[0]=(short)f2bf(cq0.x); a1[1]=(short)f2bf(cq0.y); a1[2]=(short)f2bf(cq0.z); a1[3]=(short)f2bf(cq0.w);
        a1[4]=(short)f2bf(cq1.x); a1[5]=(short)f2bf(cq1.y); a1[6]=(short)f2bf(cq1.z); a1[7]=(short)f2bf(cq1.w);
        const short8 b0 = *(const short8*)(mun + l15 * 264 + dbase + g * 8);
        const short8 b1 = *(const short8*)(mun + (16 + l15) * 264 + dbase + g * 8);
        f32x4 cc00 = __builtin_amdgcn_mfma_f32_16x16x32_bf16(a0, b0, fz, 0, 0, 0);
        f32x4 cc01 = __builtin_amdgcn_mfma_f32_16x16x32_bf16(a0, b1, fz, 0, 0, 0);
        f32x4 cc10 = __builtin_amdgcn_mfma_f32_16x16x32_bf16(a1, b0, fz, 0, 0, 0);
        f32x4 cc11 = __builtin_amdgcn_mfma_f32_16x16x32_bf16(a1, b1, fz, 0, 0, 0);
        ss0 += __shfl_xor(ss0, 16); ss0 += __shfl_xor(ss0, 32);
        ss1 += __shfl_xor(ss1, 16); ss1 += __shfl_xor(ss1, 32);

        // scatter partial c into own slab: c[s][k], s=sample, k=cluster
        float* cp = cpartf + wid * 1024;
        #pragma unroll
        for (int r = 0; r < 4; ++r) {
            cp[(4 * g + r) * 32 + l15]           = cc00[r];
            cp[(4 * g + r) * 32 + 16 + l15]      = cc01[r];
            cp[(16 + 4 * g + r) * 32 + l15]      = cc10[r];
            cp[(16 + 4 * g + r) * 32 + 16 + l15] = cc11[r];
        }
        if (g == 0) {
            ssg[wid * 32 + l15] = ss0;
            ssg[wid * 32 + 16 + l15] = ss1;
        }
        __syncthreads();

        // ---- phase C: split softmax — wave w owns samples 4w..4w+3 ----
        #pragma unroll
        for (int p = 0; p < 2; ++p) {
            const int s = 4 * wid + 2 * p + (lane >> 5);
            const int kk = lane & 31;
            float craw = 0.f, sss = 0.f;
            #pragma unroll
            for (int w2 = 0; w2 < 8; ++w2) {
                craw += cpartf[w2 * 1024 + s * 32 + kk];
                sss += ssg[w2 * 32 + s];
            }
            const float inv = 1.0f / fmaxf(sqrtf(sss), EPSF);
            const float c = craw * inv;
            const float l = kpv * c;
            float m = l;
            m = fmaxf(m, __shfl_xor(m, 1));
            m = fmaxf(m, __shfl_xor(m, 2));
            m = fmaxf(m, __shfl_xor(m, 4));
            m = fmaxf(m, __shfl_xor(m, 8));
            m = fmaxf(m, __shfl_xor(m, 16));
            const float e = __expf(l - m);
            float z = e;
            z += __shfl_xor(z, 1);
            z += __shfl_xor(z, 2);
            z += __shfl_xor(z, 4);
            z += __shfl_xor(z, 8);
            z += __shfl_xor(z, 16);
            const float gam = e / z;
            const float u = gam * rsqrtf(fmaxf(1.0f - c * c + EPSF, 1e-12f));
            Sacc += u * c;
            Gacc += gam * (kpv * (1.0f - c) - 1.0f);
            wTs[kk * 40 + s] = f2bf(u * inv);
        }
        __syncthreads();

        // ---- phase D: GEMM2: A[k][own 32 d's] += w~^T x ----
        const short8 wa0 = *(const short8*)(wTs + l15 * 40 + g * 8);
        const short8 wa1 = *(const short8*)(wTs + (16 + l15) * 40 + g * 8);
        float xf0[8], xf1[8];
        #pragma unroll
        for (int e = 0; e < 8; ++e) {
            xf0[e] = xcur[(g * 8 + e) * 256 + dbase + l15];
            xf1[e] = xcur[(g * 8 + e) * 256 + dbase + 16 + l15];
        }
        short8 xb0, xb1;
        #pragma unroll
        for (int e = 0; e < 8; ++e) {
            xb0[e] = (short)f2bf(xf0[e]);
            xb1[e] = (short)f2bf(xf1[e]);
        }
        acc00 = __builtin_amdgcn_mfma_f32_16x16x32_bf16(wa0, xb0, acc00, 0, 0, 0);
        acc01 = __builtin_amdgcn_mfma_f32_16x16x32_bf16(wa0, xb1, acc01, 0, 0, 0);
        acc10 = __builtin_amdgcn_mfma_f32_16x16x32_bf16(wa1, xb0, acc10, 0, 0, 0);
        acc11 = __builtin_amdgcn_mfma_f32_16x16x32_bf16(wa1, xb1, acc11, 0, 0, 0);
    }

    // ---- epilogue: S/G block-reduce + bf16-packed A partial ----
    Sacc += __shfl_xor(Sacc, 32);
    Gacc += __shfl_xor(Gacc, 32);
    if (lane < 32) {
        sgbuf[wid * 64 + lane] = Sacc;
        sgbuf[wid * 64 + 32 + lane] = Gacc;
    }
    __syncthreads();
    unsigned* Pb = P + (size_t)blockIdx.x * PSTR;
    #pragma unroll
    for (int r = 0; r < 4; ++r) {
        unsigned lo0 = f2bf(acc00[r]), hi0 = f2bf(acc10[r]);
        unsigned lo1 = f2bf(acc01[r]), hi1 = f2bf(acc11[r]);
        Pb[(4 * g + r) * 256 + dbase + l15]      = (hi0 << 16) | lo0;
        Pb[(4 * g + r) * 256 + dbase + 16 + l15] = (hi1 << 16) | lo1;
    }
    if (tid < 64) {
        float v = 0.f;
        #pragma unroll
        for (int w = 0; w < 8; ++w) v += sgbuf[w * 64 + tid];
        ((float*)(Pb + 4096))[tid] = v;   // [0..31]=S_k, [32..63]=G_k
    }
}

// Fused finalize: blocks 0..255: k-pair (b>>4) x d-chunk (b&15); block 256: G.
__global__ void __launch_bounds__(256)
spf_fin(const unsigned* __restrict__ P, const float* __restrict__ mu,
        const float* __restrict__ kappa, float* __restrict__ out, int nb, float invN) {
    __shared__ float r0[256], r1[256];
    const int b = blockIdx.x, t = threadIdx.x;
    if (b < 256) {
        const int kp = b >> 4, dc = b & 15;
        const int dd = t & 15, bq = t >> 4;
        const int d = dc * 16 + dd;
        float A0 = 0.f, A1 = 0.f;
        for (int b2 = bq; b2 < nb; b2 += 16) {
            unsigned v = P[(size_t)b2 * PSTR + kp * 256 + d];
            A0 += bflo(v); A1 += bfhi(v);
        }
        r0[t] = A0; r1[t] = A1;
        __syncthreads();
        #pragma unroll
        for (int off = 128; off >= 16; off >>= 1) {
            if (t < off) { r0[t] += r0[t + off]; r1[t] += r1[t + off]; }
            __syncthreads();
        }
        const float A0f = r0[dd], A1f = r1[dd];
        __syncthreads();
        // Sk
        float s0 = 0.f, s1 = 0.f;
        for (int b2 = t; b2 < nb; b2 += 256) {
            const float* Sf = (const float*)(P + (size_t)b2 * PSTR + 4096);
            s0 += Sf[kp]; s1 += Sf[16 + kp];
        }
        r0[t] = s0; r1[t] = s1;
        __syncthreads();
        #pragma unroll
        for (int off = 128; off >= 1; off >>= 1) {
            if (t < off) { r0[t] += r0[t + off]; r1[t] += r1[t + off]; }
            __syncthreads();
        }
        const float Sk0 = r0[0], Sk1 = r1[0];
        __syncthreads();
        // mu row norms
        const float m0 = mu[kp * 256 + t], m1 = mu[(16 + kp) * 256 + t];
        r0[t] = m0 * m0; r1[t] = m1 * m1;
        __syncthreads();
        #pragma unroll
        for (int off = 128; off >= 1; off >>= 1) {
            if (t < off) { r0[t] += r0[t + off]; r1[t] += r1[t + off]; }
            __syncthreads();
        }
        const float inv0 = 1.0f / fmaxf(sqrtf(r0[0]), EPSF);
        const float inv1 = 1.0f / fmaxf(sqrtf(r1[0]), EPSF);
        if (t < 16) {
            const float sq0 = sqrtf(fmaxf(kappa[kp], EPSF));
            const float sq1 = sqrtf(fmaxf(kappa[16 + kp], EPSF));
            const int dO = dc * 16 + t;
            out[kp * 256 + dO]        = sq0 * (A0f - Sk0 * mu[kp * 256 + dO] * inv0) * invN;
            out[(16 + kp) * 256 + dO] = sq1 * (A1f - Sk1 * mu[(16 + kp) * 256 + dO] * inv1) * invN;
        }
    } else {
        const int k = t & 31, bq = t >> 5;
        float gs = 0.f;
        for (int b2 = bq; b2 < nb; b2 += 8) {
            const float* Gf = (const float*)(P + (size_t)b2 * PSTR + 4096);
            gs += Gf[32 + k];
        }
        r0[t] = gs;
        __syncthreads();
        #pragma unroll
        for (int off = 128; off >= 32; off >>= 1) {
            if (t < off) r0[t] += r0[t + off];
            __syncthreads();
        }
        if (t < 32) out[8192 + t] = r0[t] * 0.70710678118654752f * invN;
    }
}

extern "C" void kernel_launch(void* const* d_in, const int* in_sizes, int n_in,
                              void* d_out, int out_size, void* d_ws, size_t ws_size,
                              hipStream_t stream) {
    const float* x = (const float*)d_in[0];
    const float* mu = (const float*)d_in[1];
    const float* kappa = (const float*)d_in[2];
    unsigned* P = (unsigned*)d_ws;
    float* out = (float*)d_out;
    const int N = in_sizes[0] / 256;
    const int ntiles = N / 32;
    int nb = ntiles < 512 ? ntiles : 512;
    while (nb > 1 && (size_t)nb * PSTR * 4 > ws_size) nb >>= 1;

    spf_main<<<nb, 512, 0, stream>>>(x, mu, kappa, P, ntiles);
    spf_fin<<<257, 256, 0, stream>>>(P, mu, kappa, out, nb, 1.0f / (float)N);
}